// Round 13
// baseline (26.108 us; speedup 1.0000x reference)
//
#include <hip/hip_runtime.h>
#include <math.h>

#define NG  8
#define DH  8
#define NCP 4     // channel pairs
#define KS  7
#define PAD 3
#define TH  16    // tile rows per block
#define TW  32    // tile col span (block covers ONE parity: 16 outputs/row)
#define TPH 22    // padded tile rows
#define RSTW 40   // LDS row stride in h2-words (38 cols + 2 pad)
#define PLW  (TPH * RSTW)   // 880 h2-words per cp-plane
#define CH  64
#define HH  64
#define WW  64

typedef __fp16 h2v __attribute__((ext_vector_type(2)));
typedef __fp16 h4v __attribute__((ext_vector_type(4)));

#if __has_builtin(__builtin_amdgcn_exp2f)
#define EXP2(x) __builtin_amdgcn_exp2f(x)
#else
#define EXP2(x) exp2f(x)
#endif

__device__ __forceinline__ int imin(int a, int b) { return a < b ? a : b; }
__device__ __forceinline__ int imax(int a, int b) { return a > b ? a : b; }

__global__ __launch_bounds__(256, 2)   // cap 128 VGPR -> 4 blocks/CU = 4 waves/SIMD
void saconv_kernel(const float* __restrict__ x,
                   const float* __restrict__ wq,
                   const float* __restrict__ wk,
                   const float* __restrict__ wv,
                   const float* __restrict__ relh,
                   const float* __restrict__ relw,
                   float* __restrict__ out) {
  // Parity-shifted tile: word c of a plane = x[b, ch, h0+row-3, w0 + par + c - 3]
  // => every output's 7-col window starts at EVEN word 2*tx (aligned b64, static idx).
  __shared__ h2v xs2[NCP * PLW];        // 14.1 KB
  __shared__ float swq[DH * DH];
  __shared__ float swk[DH * DH];
  __shared__ float swv[DH * DH];
  __shared__ float srel[DH * KS];

  const int tx  = threadIdx.x;          // 0..15 : output column (this parity)
  const int ty  = threadIdx.y;          // 0..15 : output row
  const int tid = ty * 16 + tx;
  const int gx  = blockIdx.x;           // 0..3 : (tile_x, parity)
  const int par = gx & 1;
  const int w0  = (gx >> 1) * TW;
  const int bz  = blockIdx.z;
  const int b   = bz >> 3;
  const int g   = bz & 7;
  const int h0  = blockIdx.y * TH;

  // ---- stage weights + rel table ----
  if (tid < DH * DH) swq[tid] = wq[g * DH * DH + tid];
  else if (tid < 2 * DH * DH) swk[tid - 64] = wk[g * DH * DH + tid - 64];
  else if (tid < 3 * DH * DH) swv[tid - 128] = wv[g * DH * DH + tid - 128];
  else if (tid < 3 * DH * DH + DH * KS) {
    int t2 = tid - 192;
    int c = t2 / KS, t = t2 - c * KS;
    int gc = g * DH + c;
    srel[t2] = (g < 4) ? relh[gc * KS + t] : relw[(gc - 32) * KS + t];
  }

  // ---- stage parity-shifted zero-padded x tile as f16 channel-pairs ----
  const float* xb = x + (size_t)(b * CH + g * DH) * (HH * WW);
  const int NCHK = NCP * TPH * 19;      // 1672 b64 chunks (words 0..37)
  #pragma unroll
  for (int kk = 0; kk < 7; kk++) {
    int f = tid + kk * 256;
    if (f < NCHK) {
      int cp  = f / (TPH * 19);
      int r   = f - cp * (TPH * 19);
      int row = r / 19;
      int cc  = r - row * 19;
      int yy  = h0 + row - PAD;
      int cy  = imin(imax(yy, 0), HH - 1);
      bool yok = (yy >= 0) & (yy < HH);
      const float* p0 = xb + ((size_t)(2 * cp) * HH + cy) * WW;
      float v0[2], v1[2];
      #pragma unroll
      for (int e = 0; e < 2; e++) {
        int xx = w0 + par + 2 * cc + e - PAD;   // parity shift folded into staging
        int cx = imin(imax(xx, 0), WW - 1);
        bool inb = yok & (xx >= 0) & (xx < WW);
        float a0 = p0[cx];
        float a1 = p0[HH * WW + cx];
        v0[e] = inb ? a0 : 0.0f;
        v1[e] = inb ? a1 : 0.0f;
      }
      h2v pk0 = __builtin_amdgcn_cvt_pkrtz(v0[0], v1[0]);
      h2v pk1 = __builtin_amdgcn_cvt_pkrtz(v0[1], v1[1]);
      h4v w4 = { pk0.x, pk0.y, pk1.x, pk1.y };
      *(h4v*)&xs2[cp * PLW + row * RSTW + 2 * cc] = w4;
    }
  }
  __syncthreads();

  // ---- preamble: q, fold qk = scale*l2e*(Wk^T q) packed f16, rq = scale*l2e*(rel^T q) ----
  const float scale = 0.35355339059327373f;   // sqrt(1/8)
  const float L2E   = 1.4426950408889634f;
  h2v  qkh[NCP];
  float rq[KS];
  {
    float xc[DH];
    #pragma unroll
    for (int cp = 0; cp < NCP; cp++) {
      h2v wv2 = xs2[cp * PLW + (ty + PAD) * RSTW + (2 * tx + PAD)];  // center col
      xc[2 * cp]     = (float)wv2.x;
      xc[2 * cp + 1] = (float)wv2.y;
    }
    float q_[DH];
    #pragma unroll
    for (int c = 0; c < DH; c++) {
      float a = 0.f;
      #pragma unroll
      for (int ci = 0; ci < DH; ci++)
        a = fmaf(swq[c * DH + ci], xc[ci], a);
      q_[c] = a;
    }
    #pragma unroll
    for (int cp = 0; cp < NCP; cp++) {
      float a0 = 0.f, a1 = 0.f;
      #pragma unroll
      for (int c = 0; c < DH; c++) {
        a0 = fmaf(q_[c], swk[c * DH + 2 * cp], a0);
        a1 = fmaf(q_[c], swk[c * DH + 2 * cp + 1], a1);
      }
      qkh[cp] = __builtin_amdgcn_cvt_pkrtz(a0 * (scale * L2E), a1 * (scale * L2E));
    }
    #pragma unroll
    for (int t = 0; t < KS; t++) {
      float a = 0.f;
      #pragma unroll
      for (int c = 0; c < DH; c++)
        a = fmaf(q_[c], srel[c * KS + t], a);
      rq[t] = a * (scale * L2E);
    }
  }

  // ---- window loop: fdot2 logits (base-2), raw v_exp_f32, fma_mix accumulation ----
  const bool useI = (g < 4);

  float s = 0.f;
  float xa[DH];
  #pragma unroll
  for (int ci = 0; ci < DH; ci++) xa[ci] = 0.f;

  #pragma unroll
  for (int i = 0; i < KS; i++) {
    const int wbase = (ty + i) * RSTW + 2 * tx;
    // 8 h2-words (window uses 0..6) per cp-plane: 4x ds_read_b64
    h2v xw[NCP][8];
    #pragma unroll
    for (int cp = 0; cp < NCP; cp++) {
      const h4v* bp = (const h4v*)&xs2[cp * PLW + wbase];
      h4v r0 = bp[0], r1 = bp[1], r2 = bp[2], r3 = bp[3];
      xw[cp][0] = __builtin_shufflevector(r0, r0, 0, 1);
      xw[cp][1] = __builtin_shufflevector(r0, r0, 2, 3);
      xw[cp][2] = __builtin_shufflevector(r1, r1, 0, 1);
      xw[cp][3] = __builtin_shufflevector(r1, r1, 2, 3);
      xw[cp][4] = __builtin_shufflevector(r2, r2, 0, 1);
      xw[cp][5] = __builtin_shufflevector(r2, r2, 2, 3);
      xw[cp][6] = __builtin_shufflevector(r3, r3, 0, 1);
      xw[cp][7] = __builtin_shufflevector(r3, r3, 2, 3);
    }

    float e[KS];
    float se = 0.f;
    #pragma unroll
    for (int j = 0; j < KS; j++) {
      float d = useI ? rq[i] : rq[j];   // log2-domain, scale pre-folded
      #pragma unroll
      for (int cp = 0; cp < NCP; cp++)
        d = __builtin_amdgcn_fdot2(qkh[cp], xw[cp][j], d, false);
      e[j] = EXP2(d);
      se += e[j];
    }
    s += se;
    #pragma unroll
    for (int cp = 0; cp < NCP; cp++) {
      float a0 = xa[2 * cp];
      float a1 = xa[2 * cp + 1];
      #pragma unroll
      for (int j = 0; j < KS; j++) {
        a0 = fmaf(e[j], (float)xw[cp][j].x, a0);   // v_fma_mix_f32
        a1 = fmaf(e[j], (float)xw[cp][j].y, a1);
      }
      xa[2 * cp]     = a0;
      xa[2 * cp + 1] = a1;
    }
  }

  // ---- epilogue: out = Wv * (xa / s), scalar stores (stride-2 cols) ----
  float inv = 1.0f / s;
  #pragma unroll
  for (int ci = 0; ci < DH; ci++) xa[ci] *= inv;

  const int h = h0 + ty;
  const int wcol = w0 + 2 * tx + par;
  float* ob = out + (((size_t)(b * CH + g * DH) * HH + h) * WW + wcol);
  #pragma unroll
  for (int c = 0; c < DH; c++) {
    float a = 0.f;
    #pragma unroll
    for (int ci = 0; ci < DH; ci++)
      a = fmaf(swv[c * DH + ci], xa[ci], a);
    ob[(size_t)c * (HH * WW)] = a;
  }
}

extern "C" void kernel_launch(void* const* d_in, const int* in_sizes, int n_in,
                              void* d_out, int out_size, void* d_ws, size_t ws_size,
                              hipStream_t stream) {
  const float* x    = (const float*)d_in[0];
  // d_in[1] = r, unused by the reference computation
  const float* wq   = (const float*)d_in[2];
  const float* wk   = (const float*)d_in[3];
  const float* wv   = (const float*)d_in[4];
  const float* relh = (const float*)d_in[5];
  const float* relw = (const float*)d_in[6];
  float* out = (float*)d_out;

  const int B = in_sizes[0] / (CH * HH * WW);   // 8
  dim3 grid((WW / TW) * 2, HH / TH, B * NG);    // 4 x 4 x 64 = 1024 blocks (x = tile*2+parity)
  dim3 block(16, 16, 1);                        // 256 threads = 4 waves
  saconv_kernel<<<grid, block, 0, stream>>>(x, wq, wk, wv, relh, relw, out);
}

// Round 14
// 18.567 us; speedup vs baseline: 1.4061x; 1.4061x over previous
//
#include <hip/hip_runtime.h>
#include <math.h>

#define NG  8
#define DH  8
#define NCP 4     // channel pairs
#define KS  7
#define PAD 3
#define TH  16    // tile rows
#define TW  32    // tile cols
#define OW  2     // outputs per thread along W
#define TPH 22    // padded tile rows
#define RSTW 40   // LDS row stride in h2-words (38 cols + 2 pad)
#define PLW  (TPH * RSTW)   // 880 words per cp-plane
#define CH  64
#define HH  64
#define WW  64

typedef __fp16 h2v __attribute__((ext_vector_type(2)));
typedef __fp16 h4v __attribute__((ext_vector_type(4)));

#if __has_builtin(__builtin_amdgcn_exp2f)
#define EXP2(x) __builtin_amdgcn_exp2f(x)
#else
#define EXP2(x) exp2f(x)
#endif

__device__ __forceinline__ int imin(int a, int b) { return a < b ? a : b; }
__device__ __forceinline__ int imax(int a, int b) { return a > b ? a : b; }

__global__ __launch_bounds__(256, 2)   // cap 128 VGPR -> 2 blocks/CU
void saconv_kernel(const float* __restrict__ x,
                   const float* __restrict__ wq,
                   const float* __restrict__ wk,
                   const float* __restrict__ wv,
                   const float* __restrict__ relh,
                   const float* __restrict__ relw,
                   float* __restrict__ out) {
  // xs2[cp*PLW + row*RSTW + col] = h2( x[b,g*8+2cp,row',col'], x[b,g*8+2cp+1,row',col'] )
  __shared__ h2v xs2[NCP * PLW];        // 14.1 KB — the ONLY LDS use now

  const int tx  = threadIdx.x;          // 0..15 (pair of output columns)
  const int ty  = threadIdx.y;          // 0..15 (output row)
  const int tid = ty * 16 + tx;
  const int bz  = blockIdx.z;
  const int b   = bz >> 3;
  const int g   = bz & 7;               // wave-uniform -> weight reads become s_load
  const int h0  = blockIdx.y * TH;
  const int w0  = blockIdx.x * TW;

  // ---- stage zero-padded x tile as f16 channel-pairs (b64 = 2 cols) ----
  const float* xb = x + (size_t)(b * CH + g * DH) * (HH * WW);
  const int NCHK = NCP * TPH * 19;      // 1672 b64 chunks (cols 0..37)
  #pragma unroll
  for (int kk = 0; kk < 7; kk++) {
    int f = tid + kk * 256;
    if (f < NCHK) {
      int cp  = f / (TPH * 19);
      int r   = f - cp * (TPH * 19);
      int row = r / 19;
      int cc  = r - row * 19;
      int yy  = h0 + row - PAD;
      int cy  = imin(imax(yy, 0), HH - 1);
      bool yok = (yy >= 0) & (yy < HH);
      const float* p0 = xb + ((size_t)(2 * cp) * HH + cy) * WW;
      float v0[2], v1[2];
      #pragma unroll
      for (int e = 0; e < 2; e++) {
        int xx = w0 + 2 * cc + e - PAD;
        int cx = imin(imax(xx, 0), WW - 1);
        bool inb = yok & (xx >= 0) & (xx < WW);
        float a0 = p0[cx];
        float a1 = p0[HH * WW + cx];
        v0[e] = inb ? a0 : 0.0f;
        v1[e] = inb ? a1 : 0.0f;
      }
      h2v pk0 = __builtin_amdgcn_cvt_pkrtz(v0[0], v1[0]);   // col 2cc: (ch lo, ch hi)
      h2v pk1 = __builtin_amdgcn_cvt_pkrtz(v0[1], v1[1]);   // col 2cc+1
      h4v w4 = { pk0.x, pk0.y, pk1.x, pk1.y };
      *(h4v*)&xs2[cp * PLW + row * RSTW + 2 * cc] = w4;
    }
  }
  // NOTE: no barrier yet — preamble below reads only GLOBAL data, so it
  // executes in the shadow of the staging loads/writes.

  // ---- preamble: q from global center pixels; weights via uniform s_load ----
  const float sl2e = 0.35355339059327373f * 1.4426950408889634f; // scale*log2(e)
  h2v  qkh[OW][NCP];
  float rq[OW][KS];
  {
    float xc[OW][DH];
    const float* xq = xb + (size_t)(h0 + ty) * WW + (w0 + 2 * tx);  // center, in-bounds
    #pragma unroll
    for (int o = 0; o < OW; o++)
      #pragma unroll
      for (int ci = 0; ci < DH; ci++)
        xc[o][ci] = xq[(size_t)ci * (HH * WW) + o];

    float q_[OW][DH];
    #pragma unroll
    for (int o = 0; o < OW; o++)
      #pragma unroll
      for (int c = 0; c < DH; c++) {
        float a = 0.f;
        #pragma unroll
        for (int ci = 0; ci < DH; ci++)
          a = fmaf(wq[(g * DH + c) * DH + ci], xc[o][ci], a);   // s_load weight
        q_[o][c] = a;
      }
    #pragma unroll
    for (int o = 0; o < OW; o++)
      #pragma unroll
      for (int cp = 0; cp < NCP; cp++) {
        float a0 = 0.f, a1 = 0.f;
        #pragma unroll
        for (int c = 0; c < DH; c++) {
          a0 = fmaf(q_[o][c], wk[(g * DH + c) * DH + 2 * cp], a0);
          a1 = fmaf(q_[o][c], wk[(g * DH + c) * DH + 2 * cp + 1], a1);
        }
        qkh[o][cp] = __builtin_amdgcn_cvt_pkrtz(a0 * sl2e, a1 * sl2e);
      }
    if (g < 4) {
      #pragma unroll
      for (int o = 0; o < OW; o++)
        #pragma unroll
        for (int t = 0; t < KS; t++) {
          float a = 0.f;
          #pragma unroll
          for (int c = 0; c < DH; c++)
            a = fmaf(q_[o][c], relh[(g * DH + c) * KS + t], a);
          rq[o][t] = a * sl2e;
        }
    } else {
      #pragma unroll
      for (int o = 0; o < OW; o++)
        #pragma unroll
        for (int t = 0; t < KS; t++) {
          float a = 0.f;
          #pragma unroll
          for (int c = 0; c < DH; c++)
            a = fmaf(q_[o][c], relw[((g - 4) * DH + c) * KS + t], a);
          rq[o][t] = a * sl2e;
        }
    }
  }
  __syncthreads();   // xs2 ready for all

  // ---- window loop: fdot2 logits (base-2), raw exp2, fma_mix accumulation ----
  float s[OW], xa[OW][DH];
  #pragma unroll
  for (int o = 0; o < OW; o++) {
    s[o] = 0.f;
    #pragma unroll
    for (int ci = 0; ci < DH; ci++) xa[o][ci] = 0.f;
  }

  // Loop body macro; DINIT selects rq[o][i] (rel_h groups) vs rq[o][j] (rel_w groups)
  // with the uniform branch hoisted OUTSIDE the loop (saves 98 cndmasks/thread).
#define WINLOOP(DINIT)                                                         \
  _Pragma("unroll")                                                            \
  for (int i = 0; i < KS; i++) {                                               \
    const int wbase = (ty + i) * RSTW + 2 * tx;                                \
    h2v xw[NCP][8];                                                            \
    _Pragma("unroll")                                                          \
    for (int cp = 0; cp < NCP; cp++) {                                         \
      const h2v* bp = &xs2[cp * PLW + wbase];                                  \
      _Pragma("unroll")                                                        \
      for (int k = 0; k < 8; k++) xw[cp][k] = bp[k];                           \
    }                                                                          \
    _Pragma("unroll")                                                          \
    for (int o = 0; o < OW; o++) {                                             \
      float e[KS];                                                             \
      float se = 0.f;                                                          \
      _Pragma("unroll")                                                        \
      for (int j = 0; j < KS; j++) {                                           \
        float d = (DINIT);                                                     \
        _Pragma("unroll")                                                      \
        for (int cp = 0; cp < NCP; cp++)                                       \
          d = __builtin_amdgcn_fdot2(qkh[o][cp], xw[cp][o + j], d, false);     \
        e[j] = EXP2(d);                                                        \
        se += e[j];                                                            \
      }                                                                        \
      s[o] += se;                                                              \
      _Pragma("unroll")                                                        \
      for (int cp = 0; cp < NCP; cp++) {                                       \
        float a0 = xa[o][2 * cp];                                              \
        float a1 = xa[o][2 * cp + 1];                                          \
        _Pragma("unroll")                                                      \
        for (int j = 0; j < KS; j++) {                                         \
          a0 = fmaf(e[j], (float)xw[cp][o + j].x, a0);                         \
          a1 = fmaf(e[j], (float)xw[cp][o + j].y, a1);                         \
        }                                                                      \
        xa[o][2 * cp]     = a0;                                                \
        xa[o][2 * cp + 1] = a1;                                                \
      }                                                                        \
    }                                                                          \
  }

  if (g < 4) { WINLOOP(rq[o][i]) }
  else       { WINLOOP(rq[o][j]) }
#undef WINLOOP

  // ---- epilogue: out = Wv * (xa / s); Wv via uniform s_load; float2 stores ----
  #pragma unroll
  for (int o = 0; o < OW; o++) {
    float inv = 1.0f / s[o];
    #pragma unroll
    for (int ci = 0; ci < DH; ci++) xa[o][ci] *= inv;
  }

  const int h = h0 + ty;
  const int wbase = w0 + 2 * tx;
  #pragma unroll
  for (int c = 0; c < DH; c++) {
    float a0 = 0.f, a1 = 0.f;
    #pragma unroll
    for (int ci = 0; ci < DH; ci++) {
      float wvv = wv[(g * DH + c) * DH + ci];
      a0 = fmaf(wvv, xa[0][ci], a0);
      a1 = fmaf(wvv, xa[1][ci], a1);
    }
    *(float2*)(&out[((size_t)(b * CH + g * DH + c) * HH + h) * WW + wbase]) =
        make_float2(a0, a1);
  }
}

extern "C" void kernel_launch(void* const* d_in, const int* in_sizes, int n_in,
                              void* d_out, int out_size, void* d_ws, size_t ws_size,
                              hipStream_t stream) {
  const float* x    = (const float*)d_in[0];
  // d_in[1] = r, unused by the reference computation
  const float* wq   = (const float*)d_in[2];
  const float* wk   = (const float*)d_in[3];
  const float* wv   = (const float*)d_in[4];
  const float* relh = (const float*)d_in[5];
  const float* relw = (const float*)d_in[6];
  float* out = (float*)d_out;

  const int B = in_sizes[0] / (CH * HH * WW);   // 8
  dim3 grid(WW / TW, HH / TH, B * NG);          // 2 x 4 x 64 = 512 blocks
  dim3 block(16, 16, 1);                        // 256 threads = 4 waves
  saconv_kernel<<<grid, block, 0, stream>>>(x, wq, wk, wv, relh, relw, out);
}

// Round 15
// 17.823 us; speedup vs baseline: 1.4648x; 1.0417x over previous
//
#include <hip/hip_runtime.h>
#include <math.h>

#define NG  8
#define DH  8
#define NCP 4     // channel pairs
#define KS  7
#define PAD 3
#define TH  16    // tile rows
#define TW  32    // tile cols
#define OW  2     // outputs per thread along W
#define TPH 22    // padded tile rows
#define RSTW 40   // LDS row stride in h2-words (38 cols + 2 pad)
#define PLW  (TPH * RSTW)   // 880 words per cp-plane
#define CH  64
#define HH  64
#define WW  64

typedef __fp16 h2v __attribute__((ext_vector_type(2)));
typedef __fp16 h4v __attribute__((ext_vector_type(4)));

#if __has_builtin(__builtin_amdgcn_exp2f)
#define EXP2(x) __builtin_amdgcn_exp2f(x)
#else
#define EXP2(x) exp2f(x)
#endif

__device__ __forceinline__ int imin(int a, int b) { return a < b ? a : b; }
__device__ __forceinline__ int imax(int a, int b) { return a > b ? a : b; }

__global__ __launch_bounds__(256, 1)   // VGPR in (128,256] keeps 8 waves/CU (m69 step) = R12 residency
void saconv_kernel(const float* __restrict__ x,
                   const float* __restrict__ wq,
                   const float* __restrict__ wk,
                   const float* __restrict__ wv,
                   const float* __restrict__ relh,
                   const float* __restrict__ relw,
                   float* __restrict__ out) {
  // xs2[cp*PLW + row*RSTW + col] = h2( x[b,g*8+2cp,row',col'], x[b,g*8+2cp+1,row',col'] )
  __shared__ h2v xs2[NCP * PLW];        // 14.1 KB
  __shared__ float swq[DH * DH];
  __shared__ float swk[DH * DH];
  __shared__ float swv[DH * DH];
  __shared__ float srel[DH * KS];

  const int tx  = threadIdx.x;          // 0..15 (pair of output columns)
  const int ty  = threadIdx.y;          // 0..15 (output row)
  const int tid = ty * 16 + tx;
  const int bz  = blockIdx.z;
  const int b   = bz >> 3;
  const int g   = bz & 7;
  const int h0  = blockIdx.y * TH;
  const int w0  = blockIdx.x * TW;

  // ---- stage weights + rel table ----
  if (tid < DH * DH) swq[tid] = wq[g * DH * DH + tid];
  else if (tid < 2 * DH * DH) swk[tid - 64] = wk[g * DH * DH + tid - 64];
  else if (tid < 3 * DH * DH) swv[tid - 128] = wv[g * DH * DH + tid - 128];
  else if (tid < 3 * DH * DH + DH * KS) {
    int t2 = tid - 192;
    int c = t2 / KS, t = t2 - c * KS;
    int gc = g * DH + c;
    srel[t2] = (g < 4) ? relh[gc * KS + t] : relw[(gc - 32) * KS + t];
  }

  // ---- stage zero-padded x tile as f16 channel-pairs (b64 = 2 cols) ----
  const float* xb = x + (size_t)(b * CH + g * DH) * (HH * WW);
  const int NCHK = NCP * TPH * 19;      // 1672 b64 chunks (cols 0..37)
  #pragma unroll
  for (int kk = 0; kk < 7; kk++) {
    int f = tid + kk * 256;
    if (f < NCHK) {
      int cp  = f / (TPH * 19);
      int r   = f - cp * (TPH * 19);
      int row = r / 19;
      int cc  = r - row * 19;
      int yy  = h0 + row - PAD;
      int cy  = imin(imax(yy, 0), HH - 1);
      bool yok = (yy >= 0) & (yy < HH);
      const float* p0 = xb + ((size_t)(2 * cp) * HH + cy) * WW;
      float v0[2], v1[2];
      #pragma unroll
      for (int e = 0; e < 2; e++) {
        int xx = w0 + 2 * cc + e - PAD;
        int cx = imin(imax(xx, 0), WW - 1);
        bool inb = yok & (xx >= 0) & (xx < WW);
        float a0 = p0[cx];
        float a1 = p0[HH * WW + cx];
        v0[e] = inb ? a0 : 0.0f;
        v1[e] = inb ? a1 : 0.0f;
      }
      h2v pk0 = __builtin_amdgcn_cvt_pkrtz(v0[0], v1[0]);   // col 2cc: (ch lo, ch hi)
      h2v pk1 = __builtin_amdgcn_cvt_pkrtz(v0[1], v1[1]);   // col 2cc+1
      h4v w4 = { pk0.x, pk0.y, pk1.x, pk1.y };
      *(h4v*)&xs2[cp * PLW + row * RSTW + 2 * cc] = w4;
    }
  }
  __syncthreads();

  // ---- preamble: q, fold qk = scale*l2e*(Wk^T q) packed f16, rq = scale*l2e*(rel^T q) ----
  const float scale = 0.35355339059327373f;   // sqrt(1/8)
  const float L2E   = 1.4426950408889634f;
  h2v  qkh[OW][NCP];
  float rq[OW][KS];
  {
    float xc[OW][DH];
    #pragma unroll
    for (int o = 0; o < OW; o++)
      #pragma unroll
      for (int cp = 0; cp < NCP; cp++) {
        h2v wv2 = xs2[cp * PLW + (ty + PAD) * RSTW + (2 * tx + o + PAD)];
        xc[o][2 * cp]     = (float)wv2.x;
        xc[o][2 * cp + 1] = (float)wv2.y;
      }
    float q_[OW][DH];
    #pragma unroll
    for (int o = 0; o < OW; o++)
      #pragma unroll
      for (int c = 0; c < DH; c++) {
        float a = 0.f;
        #pragma unroll
        for (int ci = 0; ci < DH; ci++)
          a = fmaf(swq[c * DH + ci], xc[o][ci], a);
        q_[o][c] = a;
      }
    #pragma unroll
    for (int o = 0; o < OW; o++)
      #pragma unroll
      for (int cp = 0; cp < NCP; cp++) {
        float a0 = 0.f, a1 = 0.f;
        #pragma unroll
        for (int c = 0; c < DH; c++) {
          a0 = fmaf(q_[o][c], swk[c * DH + 2 * cp], a0);
          a1 = fmaf(q_[o][c], swk[c * DH + 2 * cp + 1], a1);
        }
        qkh[o][cp] = __builtin_amdgcn_cvt_pkrtz(a0 * (scale * L2E), a1 * (scale * L2E));
      }
    #pragma unroll
    for (int o = 0; o < OW; o++)
      #pragma unroll
      for (int t = 0; t < KS; t++) {
        float a = 0.f;
        #pragma unroll
        for (int c = 0; c < DH; c++)
          a = fmaf(q_[o][c], srel[c * KS + t], a);
        rq[o][t] = a * (scale * L2E);
      }
  }

  // ---- window loop: ROW-AHEAD REGISTER DOUBLE-BUFFER (f16: 32 VGPR/buffer) ----
  // Issue row i+1's 16 ds_read_b64 before computing row i -> ~600 cyc compute cover.
  const bool useI = (g < 4);

  float s[OW], xa[OW][DH];
  #pragma unroll
  for (int o = 0; o < OW; o++) {
    s[o] = 0.f;
    #pragma unroll
    for (int ci = 0; ci < DH; ci++) xa[o][ci] = 0.f;
  }

  h2v xw[2][NCP][8];

  // preload row 0 into buffer 0
  {
    const int wb0 = ty * RSTW + 2 * tx;
    #pragma unroll
    for (int cp = 0; cp < NCP; cp++) {
      const h4v* bp = (const h4v*)&xs2[cp * PLW + wb0];
      h4v r0 = bp[0], r1 = bp[1], r2 = bp[2], r3 = bp[3];
      xw[0][cp][0] = __builtin_shufflevector(r0, r0, 0, 1);
      xw[0][cp][1] = __builtin_shufflevector(r0, r0, 2, 3);
      xw[0][cp][2] = __builtin_shufflevector(r1, r1, 0, 1);
      xw[0][cp][3] = __builtin_shufflevector(r1, r1, 2, 3);
      xw[0][cp][4] = __builtin_shufflevector(r2, r2, 0, 1);
      xw[0][cp][5] = __builtin_shufflevector(r2, r2, 2, 3);
      xw[0][cp][6] = __builtin_shufflevector(r3, r3, 0, 1);
      xw[0][cp][7] = __builtin_shufflevector(r3, r3, 2, 3);
    }
  }

  #pragma unroll
  for (int i = 0; i < KS; i++) {
    const int cur = i & 1;        // compile-time (loop fully unrolled)
    const int nxt = cur ^ 1;

    // prefetch row i+1 FIRST (independent of row-i compute)
    if (i < KS - 1) {
      const int wbn = (ty + i + 1) * RSTW + 2 * tx;
      #pragma unroll
      for (int cp = 0; cp < NCP; cp++) {
        const h4v* bp = (const h4v*)&xs2[cp * PLW + wbn];
        h4v r0 = bp[0], r1 = bp[1], r2 = bp[2], r3 = bp[3];
        xw[nxt][cp][0] = __builtin_shufflevector(r0, r0, 0, 1);
        xw[nxt][cp][1] = __builtin_shufflevector(r0, r0, 2, 3);
        xw[nxt][cp][2] = __builtin_shufflevector(r1, r1, 0, 1);
        xw[nxt][cp][3] = __builtin_shufflevector(r1, r1, 2, 3);
        xw[nxt][cp][4] = __builtin_shufflevector(r2, r2, 0, 1);
        xw[nxt][cp][5] = __builtin_shufflevector(r2, r2, 2, 3);
        xw[nxt][cp][6] = __builtin_shufflevector(r3, r3, 0, 1);
        xw[nxt][cp][7] = __builtin_shufflevector(r3, r3, 2, 3);
      }
    }

    #pragma unroll
    for (int o = 0; o < OW; o++) {
      float e[KS];
      float se = 0.f;
      #pragma unroll
      for (int j = 0; j < KS; j++) {
        float d = useI ? rq[o][i] : rq[o][j];   // log2-domain, scale pre-folded
        #pragma unroll
        for (int cp = 0; cp < NCP; cp++)
          d = __builtin_amdgcn_fdot2(qkh[o][cp], xw[cur][cp][o + j], d, false);
        e[j] = EXP2(d);
        se += e[j];
      }
      s[o] += se;
      #pragma unroll
      for (int cp = 0; cp < NCP; cp++) {
        float a0 = xa[o][2 * cp];
        float a1 = xa[o][2 * cp + 1];
        #pragma unroll
        for (int j = 0; j < KS; j++) {
          a0 = fmaf(e[j], (float)xw[cur][cp][o + j].x, a0);   // v_fma_mix_f32
          a1 = fmaf(e[j], (float)xw[cur][cp][o + j].y, a1);
        }
        xa[o][2 * cp]     = a0;
        xa[o][2 * cp + 1] = a1;
      }
    }
  }

  // ---- epilogue: out = Wv * (xa / s), float2 stores ----
  #pragma unroll
  for (int o = 0; o < OW; o++) {
    float inv = 1.0f / s[o];
    #pragma unroll
    for (int ci = 0; ci < DH; ci++) xa[o][ci] *= inv;
  }

  const int h = h0 + ty;
  const int wbase = w0 + 2 * tx;
  #pragma unroll
  for (int c = 0; c < DH; c++) {
    float2 v2;
    {
      float a0 = 0.f, a1 = 0.f;
      #pragma unroll
      for (int ci = 0; ci < DH; ci++) {
        a0 = fmaf(swv[c * DH + ci], xa[0][ci], a0);
        a1 = fmaf(swv[c * DH + ci], xa[1][ci], a1);
      }
      v2.x = a0; v2.y = a1;
    }
    *(float2*)(&out[((size_t)(b * CH + g * DH + c) * HH + h) * WW + wbase]) = v2;
  }
}

extern "C" void kernel_launch(void* const* d_in, const int* in_sizes, int n_in,
                              void* d_out, int out_size, void* d_ws, size_t ws_size,
                              hipStream_t stream) {
  const float* x    = (const float*)d_in[0];
  // d_in[1] = r, unused by the reference computation
  const float* wq   = (const float*)d_in[2];
  const float* wk   = (const float*)d_in[3];
  const float* wv   = (const float*)d_in[4];
  const float* relh = (const float*)d_in[5];
  const float* relw = (const float*)d_in[6];
  float* out = (float*)d_out;

  const int B = in_sizes[0] / (CH * HH * WW);   // 8
  dim3 grid(WW / TW, HH / TH, B * NG);          // 2 x 4 x 64 = 512 blocks
  dim3 block(16, 16, 1);                        // 256 threads = 4 waves
  saconv_kernel<<<grid, block, 0, stream>>>(x, wq, wk, wv, relh, relw, out);
}

// Round 16
// 17.451 us; speedup vs baseline: 1.4961x; 1.0214x over previous
//
#include <hip/hip_runtime.h>
#include <math.h>

#define NG  8
#define DH  8
#define NCP 4     // channel pairs
#define KS  7
#define PAD 3
#define TH  16    // tile rows
#define TW  32    // tile cols
#define OW  2     // outputs per thread along W
#define TPH 22    // padded tile rows
#define RSTW 40   // LDS row stride in h2-words (38 cols + 2 pad)
#define PLW  (TPH * RSTW)   // 880 words per cp-plane
#define CH  64
#define HH  64
#define WW  64

typedef __fp16 h2v __attribute__((ext_vector_type(2)));
typedef __fp16 h4v __attribute__((ext_vector_type(4)));

#if __has_builtin(__builtin_amdgcn_exp2f)
#define EXP2(x) __builtin_amdgcn_exp2f(x)
#else
#define EXP2(x) exp2f(x)
#endif

__device__ __forceinline__ int imin(int a, int b) { return a < b ? a : b; }
__device__ __forceinline__ int imax(int a, int b) { return a > b ? a : b; }

__global__ __launch_bounds__(256, 2)   // cap 128 VGPR (R12-proven)
void saconv_kernel(const float* __restrict__ x,
                   const float* __restrict__ wq,
                   const float* __restrict__ wk,
                   const float* __restrict__ wv,
                   const float* __restrict__ relh,
                   const float* __restrict__ relw,
                   float* __restrict__ out) {
  // xs2[cp*PLW + row*RSTW + col] = h2( x[b,g*8+2cp,row',col'], x[b,g*8+2cp+1,row',col'] )
  __shared__ h2v xs2[NCP * PLW];        // 14.1 KB
  // weights as f16 channel-pairs:
  __shared__ h2v swq2[DH * NCP];        // [c][cp]  = (wq[c][2cp], wq[c][2cp+1])
  __shared__ h2v swv2[DH * NCP];        // [c][cp]  = (wv[c][2cp], wv[c][2cp+1])
  __shared__ h2v swk2[DH * NCP];        // [ci][cP] = sl2e*(wk[2cP][ci], wk[2cP+1][ci])  (transposed)
  __shared__ h2v srel2[KS * NCP];       // [t][cP]  = sl2e*(rel[2cP][t], rel[2cP+1][t])

  const int tx  = threadIdx.x;          // 0..15 (pair of output columns)
  const int ty  = threadIdx.y;          // 0..15 (output row)
  const int tid = ty * 16 + tx;
  const int bz  = blockIdx.z;
  const int b   = bz >> 3;
  const int g   = bz & 7;
  const int h0  = blockIdx.y * TH;
  const int w0  = blockIdx.x * TW;

  const float sl2e = 0.35355339059327373f * 1.4426950408889634f;  // sqrt(1/8)*log2(e)

  // ---- stage weights as f16 pairs (124 items) ----
  if (tid < 32) {                       // swq2
    int c = tid >> 2, cp = tid & 3;
    float a0 = wq[g * 64 + c * 8 + 2 * cp];
    float a1 = wq[g * 64 + c * 8 + 2 * cp + 1];
    swq2[tid] = __builtin_amdgcn_cvt_pkrtz(a0, a1);
  } else if (tid < 64) {                // swv2
    int t2 = tid - 32;
    int c = t2 >> 2, cp = t2 & 3;
    float a0 = wv[g * 64 + c * 8 + 2 * cp];
    float a1 = wv[g * 64 + c * 8 + 2 * cp + 1];
    swv2[t2] = __builtin_amdgcn_cvt_pkrtz(a0, a1);
  } else if (tid < 96) {                // swk2 (transposed, sl2e pre-folded)
    int t2 = tid - 64;
    int ci = t2 >> 2, cP = t2 & 3;
    float a0 = wk[g * 64 + (2 * cP) * 8 + ci] * sl2e;
    float a1 = wk[g * 64 + (2 * cP + 1) * 8 + ci] * sl2e;
    swk2[t2] = __builtin_amdgcn_cvt_pkrtz(a0, a1);
  } else if (tid < 96 + KS * NCP) {     // srel2 (sl2e pre-folded)
    int t2 = tid - 96;
    int t = t2 >> 2, cP = t2 & 3;
    float a0, a1;
    if (g < 4) {
      a0 = relh[(g * 8 + 2 * cP) * KS + t];
      a1 = relh[(g * 8 + 2 * cP + 1) * KS + t];
    } else {
      a0 = relw[((g - 4) * 8 + 2 * cP) * KS + t];
      a1 = relw[((g - 4) * 8 + 2 * cP + 1) * KS + t];
    }
    srel2[t2] = __builtin_amdgcn_cvt_pkrtz(a0 * sl2e, a1 * sl2e);
  }

  // ---- stage zero-padded x tile as f16 channel-pairs (b64 = 2 cols) ----
  const float* xb = x + (size_t)(b * CH + g * DH) * (HH * WW);
  const int NCHK = NCP * TPH * 19;      // 1672 b64 chunks (cols 0..37)
  #pragma unroll
  for (int kk = 0; kk < 7; kk++) {
    int f = tid + kk * 256;
    if (f < NCHK) {
      int cp  = f / (TPH * 19);
      int r   = f - cp * (TPH * 19);
      int row = r / 19;
      int cc  = r - row * 19;
      int yy  = h0 + row - PAD;
      int cy  = imin(imax(yy, 0), HH - 1);
      bool yok = (yy >= 0) & (yy < HH);
      const float* p0 = xb + ((size_t)(2 * cp) * HH + cy) * WW;
      float v0[2], v1[2];
      #pragma unroll
      for (int e = 0; e < 2; e++) {
        int xx = w0 + 2 * cc + e - PAD;
        int cx = imin(imax(xx, 0), WW - 1);
        bool inb = yok & (xx >= 0) & (xx < WW);
        float a0 = p0[cx];
        float a1 = p0[HH * WW + cx];
        v0[e] = inb ? a0 : 0.0f;
        v1[e] = inb ? a1 : 0.0f;
      }
      h2v pk0 = __builtin_amdgcn_cvt_pkrtz(v0[0], v1[0]);
      h2v pk1 = __builtin_amdgcn_cvt_pkrtz(v0[1], v1[1]);
      h4v w4 = { pk0.x, pk0.y, pk1.x, pk1.y };
      *(h4v*)&xs2[cp * PLW + row * RSTW + 2 * cc] = w4;
    }
  }
  __syncthreads();

  // ---- preamble, all fdot2: q = Wq^T xc ; qk = sl2e*Wk^T q ; rq = sl2e*rel^T q ----
  h2v  qkh[OW][NCP];
  float rq[OW][KS];
  {
    h2v xc2[OW][NCP];
    #pragma unroll
    for (int o = 0; o < OW; o++)
      #pragma unroll
      for (int cp = 0; cp < NCP; cp++)
        xc2[o][cp] = xs2[cp * PLW + (ty + PAD) * RSTW + (2 * tx + o + PAD)];

    #pragma unroll
    for (int o = 0; o < OW; o++) {
      float q_[DH];
      #pragma unroll
      for (int c = 0; c < DH; c++) {
        float a = 0.f;
        #pragma unroll
        for (int cp = 0; cp < NCP; cp++)
          a = __builtin_amdgcn_fdot2(swq2[c * 4 + cp], xc2[o][cp], a, false);
        q_[c] = a;
      }
      h2v qp[NCP];
      #pragma unroll
      for (int cP = 0; cP < NCP; cP++)
        qp[cP] = __builtin_amdgcn_cvt_pkrtz(q_[2 * cP], q_[2 * cP + 1]);

      float qkt[DH];
      #pragma unroll
      for (int ci = 0; ci < DH; ci++) {
        float a = 0.f;
        #pragma unroll
        for (int cP = 0; cP < NCP; cP++)
          a = __builtin_amdgcn_fdot2(qp[cP], swk2[ci * 4 + cP], a, false);
        qkt[ci] = a;                    // sl2e pre-folded in swk2
      }
      #pragma unroll
      for (int cp = 0; cp < NCP; cp++)
        qkh[o][cp] = __builtin_amdgcn_cvt_pkrtz(qkt[2 * cp], qkt[2 * cp + 1]);

      #pragma unroll
      for (int t = 0; t < KS; t++) {
        float a = 0.f;
        #pragma unroll
        for (int cP = 0; cP < NCP; cP++)
          a = __builtin_amdgcn_fdot2(qp[cP], srel2[t * 4 + cP], a, false);
        rq[o][t] = a;                   // sl2e pre-folded in srel2
      }
    }
  }

  // ---- window loop (useI hoisted; R12's proven h4v b64 reads kept verbatim) ----
  float s[OW], xa[OW][DH];
  #pragma unroll
  for (int o = 0; o < OW; o++) {
    s[o] = 0.f;
    #pragma unroll
    for (int ci = 0; ci < DH; ci++) xa[o][ci] = 0.f;
  }

#define WINLOOP(DINIT)                                                         \
  _Pragma("unroll")                                                            \
  for (int i = 0; i < KS; i++) {                                               \
    const int wbase = (ty + i) * RSTW + 2 * tx;                                \
    h2v xw[NCP][8];                                                            \
    _Pragma("unroll")                                                          \
    for (int cp = 0; cp < NCP; cp++) {                                         \
      const h4v* bp = (const h4v*)&xs2[cp * PLW + wbase];                      \
      h4v r0 = bp[0], r1 = bp[1], r2 = bp[2], r3 = bp[3];                      \
      xw[cp][0] = __builtin_shufflevector(r0, r0, 0, 1);                       \
      xw[cp][1] = __builtin_shufflevector(r0, r0, 2, 3);                       \
      xw[cp][2] = __builtin_shufflevector(r1, r1, 0, 1);                       \
      xw[cp][3] = __builtin_shufflevector(r1, r1, 2, 3);                       \
      xw[cp][4] = __builtin_shufflevector(r2, r2, 0, 1);                       \
      xw[cp][5] = __builtin_shufflevector(r2, r2, 2, 3);                       \
      xw[cp][6] = __builtin_shufflevector(r3, r3, 0, 1);                       \
      xw[cp][7] = __builtin_shufflevector(r3, r3, 2, 3);                       \
    }                                                                          \
    _Pragma("unroll")                                                          \
    for (int o = 0; o < OW; o++) {                                             \
      float e[KS];                                                             \
      float se = 0.f;                                                          \
      _Pragma("unroll")                                                        \
      for (int j = 0; j < KS; j++) {                                           \
        float d = (DINIT);                                                     \
        _Pragma("unroll")                                                      \
        for (int cp = 0; cp < NCP; cp++)                                       \
          d = __builtin_amdgcn_fdot2(qkh[o][cp], xw[cp][o + j], d, false);     \
        e[j] = EXP2(d);                                                        \
        se += e[j];                                                            \
      }                                                                        \
      s[o] += se;                                                              \
      _Pragma("unroll")                                                        \
      for (int cp = 0; cp < NCP; cp++) {                                       \
        float a0 = xa[o][2 * cp];                                              \
        float a1 = xa[o][2 * cp + 1];                                          \
        _Pragma("unroll")                                                      \
        for (int j = 0; j < KS; j++) {                                         \
          a0 = fmaf(e[j], (float)xw[cp][o + j].x, a0);                         \
          a1 = fmaf(e[j], (float)xw[cp][o + j].y, a1);                         \
        }                                                                      \
        xa[o][2 * cp]     = a0;                                                \
        xa[o][2 * cp + 1] = a1;                                                \
      }                                                                        \
    }                                                                          \
  }

  if (g < 4) { WINLOOP(rq[o][i]) }
  else       { WINLOOP(rq[o][j]) }
#undef WINLOOP

  // ---- epilogue: out = Wv * (xa / s) via fdot2; float2 stores ----
  h2v xav2[OW][NCP];
  #pragma unroll
  for (int o = 0; o < OW; o++) {
    float inv = 1.0f / s[o];
    #pragma unroll
    for (int cp = 0; cp < NCP; cp++)
      xav2[o][cp] = __builtin_amdgcn_cvt_pkrtz(xa[o][2 * cp] * inv,
                                               xa[o][2 * cp + 1] * inv);
  }

  const int h = h0 + ty;
  const int wbase = w0 + 2 * tx;
  #pragma unroll
  for (int c = 0; c < DH; c++) {
    float a0 = 0.f, a1 = 0.f;
    #pragma unroll
    for (int cp = 0; cp < NCP; cp++) {
      a0 = __builtin_amdgcn_fdot2(swv2[c * 4 + cp], xav2[0][cp], a0, false);
      a1 = __builtin_amdgcn_fdot2(swv2[c * 4 + cp], xav2[1][cp], a1, false);
    }
    *(float2*)(&out[((size_t)(b * CH + g * DH + c) * HH + h) * WW + wbase]) =
        make_float2(a0, a1);
  }
}

extern "C" void kernel_launch(void* const* d_in, const int* in_sizes, int n_in,
                              void* d_out, int out_size, void* d_ws, size_t ws_size,
                              hipStream_t stream) {
  const float* x    = (const float*)d_in[0];
  // d_in[1] = r, unused by the reference computation
  const float* wq   = (const float*)d_in[2];
  const float* wk   = (const float*)d_in[3];
  const float* wv   = (const float*)d_in[4];
  const float* relh = (const float*)d_in[5];
  const float* relw = (const float*)d_in[6];
  float* out = (float*)d_out;

  const int B = in_sizes[0] / (CH * HH * WW);   // 8
  dim3 grid(WW / TW, HH / TH, B * NG);          // 2 x 4 x 64 = 512 blocks
  dim3 block(16, 16, 1);                        // 256 threads = 4 waves
  saconv_kernel<<<grid, block, 0, stream>>>(x, wq, wk, wv, relh, relw, out);
}